// Round 14
// baseline (199.075 us; speedup 1.0000x reference)
//
#include <hip/hip_runtime.h>
#include <math.h>

#define NB   2
#define LVL  4
#define QQ   4096
#define LEN  16384   // LVL*QQ
#define CH   256
#define NH   8
#define DD   32
#define PP   4
#define HL   64
#define WL   64
#define PARTN ((size_t)NB * LEN * CH)   // elements per partial buffer

typedef float    f32x4 __attribute__((ext_vector_type(4)));
typedef unsigned u32x4 __attribute__((ext_vector_type(4)));
typedef _Float16 h16x8 __attribute__((ext_vector_type(8)));
typedef _Float16 h16x2 __attribute__((ext_vector_type(2)));

__device__ __forceinline__ short h2s(_Float16 h) {
    union { _Float16 h; short s; } v; v.h = h; return v.s;
}
__device__ __forceinline__ _Float16 s2h(short s) {
    union { short s; _Float16 h; } v; v.s = s; return v.h;
}
__device__ __forceinline__ h16x2 u2h2(unsigned u) {
    union { unsigned u; h16x2 h; } v; v.u = u; return v.h;
}
__device__ __forceinline__ unsigned h22u(h16x2 h) {
    union { h16x2 h; unsigned u; } v; v.h = h; return v.u;
}

// Convert weights to fp16, transposed to [N][K], 16B-groups XOR-swizzled:
// WT[c][ (g&~7)|((g&7)^(c&7)) *8 + e ] = W[g*8+e][c]
__global__ __launch_bounds__(256) void prep_w(
    const float* __restrict__ W_val, const float* __restrict__ W_out,
    const float* __restrict__ W_off, const float* __restrict__ W_attn,
    short* __restrict__ WT_val, short* __restrict__ WT_out, short* __restrict__ WT_proj)
{
    const int id = blockIdx.x * 256 + threadIdx.x;   // 0 .. 229375
    if (id < 131072) {
        const int which = id >> 16;          // 0: W_val, 1: W_out
        const int u = id & 65535;
        const int c = u >> 8;                // WT row (output col), 0..255
        const int p = u & 255;               // stored position
        const int gp = p >> 3, e = p & 7;
        const int g = (gp & ~7) | ((gp & 7) ^ (c & 7));
        const int k = g * 8 + e;
        const float* W = which ? W_out : W_val;
        short* WT = which ? WT_out : WT_val;
        WT[(size_t)c * 256 + p] = h2s((_Float16)W[(size_t)k * 256 + c]);
    } else {
        const int u = id - 131072;           // 0 .. 98303
        const int i = u / (96 * 256);
        const int r = u % (96 * 256);
        const int c = r >> 8;                // 0..95
        const int p = r & 255;
        const int gp = p >> 3, e = p & 7;
        const int g = (gp & ~7) | ((gp & 7) ^ (c & 7));
        const int k = g * 8 + e;
        float w;
        if (c < 64) w = W_off[((size_t)i * 256 + k) * 64 + c];
        else        w = W_attn[((size_t)i * 256 + k) * 32 + (c - 64)];
        WT_proj[((size_t)i * 96 + c) * 256 + p] = h2s((_Float16)w);
    }
}

// MFMA GEMM (f16): C[M,N] = A[M,256] @ W[256,N] + bias.  BM=128, BK=64.
// MODE 0: A fp32, C fp16 (value proj)
// MODE 2: A fp32 = seq_query[ij], C fp16 proj layout, N=96 (blockIdx.y = ij)
// MODE 4: A = sum of 4 fp16 partials (Ain + k*PARTN), C fp32 (out proj)
template<int MODE, int BN, int WN, int MR, int NR>
__global__ __launch_bounds__(256) void gemm_mfma(
    const void* __restrict__ Ain, const short* __restrict__ WT,
    const float* __restrict__ bias, const float* __restrict__ bias2,
    void* __restrict__ Cout)
{
    __shared__ short sA[128 * 64];     // 16 KB, XOR-swizzled
    __shared__ short sB[BN * 256];     // pre-swizzled rows [col][K]
    const int t    = threadIdx.x;
    const int lane = t & 63;
    const int wave = t >> 6;
    const int m0   = blockIdx.x * 128;

    int i = 0, j = 0, n0 = 0;
    const float* Af = (const float*)Ain;
    const short* Ah = (const short*)Ain;
    const short* wt = WT;
    if (MODE == 2) {
        const int ij = blockIdx.y;
        i = ij >> 2; j = ij & 3;
        Af += (size_t)ij * (NB * QQ) * CH;
        wt += (size_t)i * 96 * 256;
    } else {
        n0 = blockIdx.y * BN;
        wt += (size_t)n0 * 256;
    }

    // stage B once (whole K), linear copy of pre-swizzled rows
    for (int u = t; u < BN * 32; u += 256)
        *(int4*)(sB + (size_t)u * 8) = *(const int4*)(wt + (size_t)u * 8);

    f32x4 acc[MR][NR];
    #pragma unroll
    for (int m = 0; m < MR; ++m)
        #pragma unroll
        for (int n = 0; n < NR; ++n)
            acc[m][n] = (f32x4){0.f, 0.f, 0.f, 0.f};

    const int wr = wave / WN;
    const int wc = wave % WN;
    const int rbase = wr * MR * 16;
    const int cbase = wc * NR * 16;
    const int lr  = lane & 15;
    const int lkg = lane >> 4;

    for (int ko = 0; ko < 4; ++ko) {
        // stage A[128][64] f16 swizzled (fused convert / partial-sum)
        #pragma unroll
        for (int v = 0; v < 4; ++v) {
            const int u = t + v * 256;
            const int row = u >> 3, g = u & 7;
            char* dst = (char*)sA + row * 128 + ((g ^ (row & 7)) << 4);
            const size_t aidx = (size_t)(m0 + row) * CH + ko * 64 + g * 8;
            if (MODE == 4) {
                const h16x8 a0 = *(const h16x8*)(Ah + aidx);
                const h16x8 a1 = *(const h16x8*)(Ah + aidx + PARTN);
                const h16x8 a2 = *(const h16x8*)(Ah + aidx + 2 * PARTN);
                const h16x8 a3 = *(const h16x8*)(Ah + aidx + 3 * PARTN);
                h16x8 w;
                #pragma unroll
                for (int e = 0; e < 8; ++e)
                    w[e] = (_Float16)(((float)a0[e] + (float)a1[e]) +
                                      ((float)a2[e] + (float)a3[e]));
                *(h16x8*)dst = w;
            } else {
                const float* sp = Af + aidx;
                const float4 f0 = *(const float4*)sp;
                const float4 f1 = *(const float4*)(sp + 4);
                h16x8 w;
                w[0] = (_Float16)f0.x; w[1] = (_Float16)f0.y;
                w[2] = (_Float16)f0.z; w[3] = (_Float16)f0.w;
                w[4] = (_Float16)f1.x; w[5] = (_Float16)f1.y;
                w[6] = (_Float16)f1.z; w[7] = (_Float16)f1.w;
                *(h16x8*)dst = w;
            }
        }
        __syncthreads();
        #pragma unroll
        for (int s = 0; s < 2; ++s) {
            h16x8 afr[MR], bfr[NR];
            #pragma unroll
            for (int m = 0; m < MR; ++m) {
                const int row = rbase + m * 16 + lr;
                afr[m] = *(const h16x8*)((const char*)sA + row * 128 +
                                         (((s * 4 + lkg) ^ (row & 7)) << 4));
            }
            #pragma unroll
            for (int n = 0; n < NR; ++n) {
                const int col = cbase + n * 16 + lr;
                const int g  = ko * 8 + s * 4 + lkg;
                const int gp = (g & ~7) | ((g & 7) ^ (col & 7));
                bfr[n] = *(const h16x8*)((const char*)sB + (size_t)col * 512 + (gp << 4));
            }
            #pragma unroll
            for (int m = 0; m < MR; ++m)
                #pragma unroll
                for (int n = 0; n < NR; ++n)
                    acc[m][n] = __builtin_amdgcn_mfma_f32_16x16x32_f16(afr[m], bfr[n], acc[m][n], 0, 0, 0);
        }
        __syncthreads();
    }

    // epilogue: C/D mapping col=lane&15, row=(lane>>4)*4+reg
    #pragma unroll
    for (int m = 0; m < MR; ++m) {
        #pragma unroll
        for (int n = 0; n < NR; ++n) {
            #pragma unroll
            for (int r = 0; r < 4; ++r) {
                const int row = m0 + rbase + m * 16 + (lane >> 4) * 4 + r;
                const int col = cbase + n * 16 + lr;
                const float v = acc[m][n][r];
                if (MODE == 0) {
                    ((short*)Cout)[(size_t)row * CH + n0 + col] = h2s((_Float16)(v + bias[n0 + col]));
                } else if (MODE == 4) {
                    ((float*)Cout)[(size_t)row * CH + n0 + col] = v + bias[n0 + col];
                } else {
                    const int nb = row >> 12, q = row & 4095;
                    const float bc = (col < 64) ? bias[i * 64 + col] : bias2[i * 32 + (col - 64)];
                    ((short*)Cout)[((((size_t)nb * LVL + i) * QQ + q) * LVL + j) * 96 + col] = h2s((_Float16)(v + bc));
                }
            }
        }
    }
}

// Sampler: one (n,level) per block (combo = bid&7 -> XCD-pinned under %8
// round-robin; 2.1 MB value slice per XCD L2). 16 queries/block, 4 waves.
// Round-12 structure; streaming accesses (proj/ref staging, output stores)
// are NON-TEMPORAL so the L2 stays dedicated to the value slice.
#define SQB 16
__global__ __launch_bounds__(256) void sampler(
    const short* __restrict__ proj,              // (NB*LEN, 384) fp16
    const float* __restrict__ ref_pts,           // (NB, LEN, LVL, 2)
    const short* __restrict__ value,             // (NB, LEN, 256) fp16
    short* __restrict__ out_part)                // 4 partials of (NB*LEN, 256)
{
    const int bid   = blockIdx.x;
    const int combo = bid & 7;                   // XCD id under %8 round-robin
    const int n     = combo >> 2;                // batch
    const int l     = combo & 3;                 // level
    const int chunk = bid >> 3;                  // 0..1023
    const int iq0   = chunk * SQB;
    const int qf0   = n * LEN + iq0;             // flat query base
    const int t     = threadIdx.x;

    // s_raw[q]: shorts 0..63 = my level's offsets, 64..191 = attn logits (all lv)
    __shared__ short s_raw[SQB][192];            // 6 KB
    __shared__ float s_ref[SQB][2];              // 128 B
    __shared__ float s_aw [SQB][NH][PP];         // 2 KB
    __shared__ int   s_off[SQB][32][4];          // 8 KB (byte offsets)
    __shared__ short s_wh [SQB][32][4];          // 4 KB (fp16 w*aw)

    // Phase A: stage proj at 64B-line granularity — NON-TEMPORAL (streaming)
    for (int u = t; u < SQB * 96; u += 256) {
        const int q = u / 96, w = u % 96;
        const unsigned* row = (const unsigned*)(proj + (size_t)(qf0 + q) * 384);
        unsigned d;
        if (w < 32) d = __builtin_nontemporal_load(&row[l * 48 + w]);
        else        d = __builtin_nontemporal_load(&row[((w - 32) >> 4) * 48 + 32 + ((w - 32) & 15)]);
        ((unsigned*)&s_raw[q][0])[w] = d;
    }
    if (t < SQB * 2) {
        const int q = t >> 1, xy = t & 1;
        s_ref[q][xy] = __builtin_nontemporal_load(
            &ref_pts[((size_t)(qf0 + q) * LVL + l) * 2 + xy]);
    }
    __syncthreads();

    // Phase B1: softmax, one thread per (q,h); keep aw of my level
    if (t < SQB * NH) {
        const int q = t >> 3, h = t & 7;
        float lg[16];
        #pragma unroll
        for (int jj = 0; jj < LVL; ++jj)
            #pragma unroll
            for (int p = 0; p < PP; ++p)
                lg[jj * 4 + p] = (float)s2h(s_raw[q][64 + jj * 32 + h * 4 + p]);
        float m = -1e30f;
        #pragma unroll
        for (int e = 0; e < 16; ++e) m = fmaxf(m, lg[e]);
        float s = 0.f;
        #pragma unroll
        for (int e = 0; e < 16; ++e) { lg[e] = __expf(lg[e] - m); s += lg[e]; }
        const float inv = 1.f / s;
        #pragma unroll
        for (int p = 0; p < PP; ++p)
            s_aw[q][h][p] = lg[l * 4 + p] * inv;
    }
    __syncthreads();

    // Phase B2: corner tables, items (q,p,h) = 512 -> 2 per thread
    for (int e = t; e < SQB * 32; e += 256) {
        const int q = e >> 5, r = e & 31;
        const int p = (r >> 3) & 3, h = r & 7;
        const float ox = (float)s2h(s_raw[q][h * 8 + p * 2 + 0]);
        const float oy = (float)s2h(s_raw[q][h * 8 + p * 2 + 1]);
        const float aw = s_aw[q][h][p];
        const float px = s_ref[q][0] * (float)WL + ox - 0.5f;
        const float py = s_ref[q][1] * (float)HL + oy - 0.5f;
        const float x0f = floorf(px), y0f = floorf(py);
        const float dx = px - x0f,   dy = py - y0f;
        const int   x0 = (int)x0f,   y0 = (int)y0f;
        #pragma unroll
        for (int c = 0; c < 4; ++c) {
            const int cx = c & 1, cy = c >> 1;
            const int gx = x0 + cx, gy = y0 + cy;
            const bool valid = ((unsigned)gx < (unsigned)WL) && ((unsigned)gy < (unsigned)HL);
            const int cgx = min(max(gx, 0), WL - 1);
            const int cgy = min(max(gy, 0), HL - 1);
            const float w = (cx ? dx : 1.f - dx) * (cy ? dy : 1.f - dy);
            const float wa = valid ? w * aw : 0.f;
            s_off[q][r][c] = (l * QQ + cgy * WL + cgx) * (CH * 2);
            s_wh [q][r][c] = h2s((_Float16)wa);
        }
    }
    __syncthreads();

    // Main: wave wv, lanes = (qsub, h, d8). 4 half-batches (2 points, 8 loads
    // each); half-batch k = query (k>>1)*8 + wv*2 + qsub, points (k&1)*2..+1.
    const int lane = t & 63;
    const int wv   = t >> 6;
    const int qsub = lane >> 5;
    const int h    = (lane >> 2) & 7;
    const int d8   = lane & 3;
    const unsigned chan = (unsigned)(h * 64 + d8 * 16);  // byte offset of 8 ch
    const short* vbase = value + (size_t)n * LEN * CH;
    short* outp = out_part + (size_t)l * PARTN;

    uint4 g0[8], g1[8];
    h16x2 a0 = (h16x2)0, a1 = (h16x2)0, a2 = (h16x2)0, a3 = (h16x2)0;

#define ISSUEH(BUF, K) do {                                                  \
    const int q_ = ((K) >> 1) * 8 + wv * 2 + qsub;                           \
    const int ph = ((K) & 1) * 2;                                            \
    _Pragma("unroll")                                                        \
    for (int pp = 0; pp < 2; ++pp) {                                         \
        const int r = (ph + pp) * 8 + h;                                     \
        const int4 offs = *(const int4*)&s_off[q_][r][0];                    \
        asm volatile("global_load_dwordx4 %0, %1, %2"                        \
            : "=v"(BUF[pp * 4 + 0]) : "v"((unsigned)offs.x + chan), "s"(vbase)); \
        asm volatile("global_load_dwordx4 %0, %1, %2"                        \
            : "=v"(BUF[pp * 4 + 1]) : "v"((unsigned)offs.y + chan), "s"(vbase)); \
        asm volatile("global_load_dwordx4 %0, %1, %2"                        \
            : "=v"(BUF[pp * 4 + 2]) : "v"((unsigned)offs.z + chan), "s"(vbase)); \
        asm volatile("global_load_dwordx4 %0, %1, %2"                        \
            : "=v"(BUF[pp * 4 + 3]) : "v"((unsigned)offs.w + chan), "s"(vbase)); \
    }                                                                        \
} while (0)

#define CONSUMEH(BUF, K) do {                                                \
    const int q_ = ((K) >> 1) * 8 + wv * 2 + qsub;                           \
    const int ph = ((K) & 1) * 2;                                            \
    if (((K) & 1) == 0) {                                                    \
        a0 = (h16x2)0; a1 = (h16x2)0; a2 = (h16x2)0; a3 = (h16x2)0;          \
    }                                                                        \
    _Pragma("unroll")                                                        \
    for (int pp = 0; pp < 2; ++pp) {                                         \
        const int r = (ph + pp) * 8 + h;                                     \
        const ushort4 ws = *(const ushort4*)&s_wh[q_][r][0];                 \
        _Pragma("unroll")                                                    \
        for (int c = 0; c < 4; ++c) {                                        \
            const unsigned short wu = (c == 0) ? ws.x : (c == 1) ? ws.y      \
                                     : (c == 2) ? ws.z : ws.w;               \
            h16x2 w; w[0] = s2h((short)wu); w[1] = w[0];                     \
            const uint4 gv = BUF[pp * 4 + c];                                \
            a0 += w * u2h2(gv.x); a1 += w * u2h2(gv.y);                      \
            a2 += w * u2h2(gv.z); a3 += w * u2h2(gv.w);                      \
        }                                                                    \
    }                                                                        \
    if ((K) & 1) {                                                           \
        u32x4 st;                                                            \
        st.x = h22u(a0); st.y = h22u(a1); st.z = h22u(a2); st.w = h22u(a3);  \
        __builtin_nontemporal_store(st,                                      \
            (u32x4*)(outp + (size_t)(qf0 + q_) * CH + h * DD + d8 * 8));     \
    }                                                                        \
} while (0)

    ISSUEH(g0, 0);
    ISSUEH(g1, 1);
    asm volatile("s_waitcnt vmcnt(8)" ::: "memory");   // g0@0 ready
    __builtin_amdgcn_sched_barrier(0);
    CONSUMEH(g0, 0);                                   // no store (K even)
    ISSUEH(g0, 2);
    asm volatile("s_waitcnt vmcnt(8)" ::: "memory");   // g1@1 ready
    __builtin_amdgcn_sched_barrier(0);
    CONSUMEH(g1, 1);                                   // + store (vmcnt +1)
    ISSUEH(g1, 3);
    asm volatile("s_waitcnt vmcnt(9)" ::: "memory");   // g0@2 ready (store+g1@3=9)
    __builtin_amdgcn_sched_barrier(0);
    CONSUMEH(g0, 2);                                   // no store
    asm volatile("s_waitcnt vmcnt(0)" ::: "memory");   // drain tail
    __builtin_amdgcn_sched_barrier(0);
    CONSUMEH(g1, 3);                                   // + store

#undef ISSUEH
#undef CONSUMEH
}

extern "C" void kernel_launch(void* const* d_in, const int* in_sizes, int n_in,
                              void* d_out, int out_size, void* d_ws, size_t ws_size,
                              hipStream_t stream) {
    const float* seq_query = (const float*)d_in[0];
    const float* ref_pts   = (const float*)d_in[1];
    const float* input_fl  = (const float*)d_in[2];
    const float* W_off     = (const float*)d_in[3];
    const float* b_off     = (const float*)d_in[4];
    const float* W_attn    = (const float*)d_in[5];
    const float* b_attn    = (const float*)d_in[6];
    const float* W_val     = (const float*)d_in[7];
    const float* b_val     = (const float*)d_in[8];
    const float* W_out     = (const float*)d_in[9];
    const float* b_out     = (const float*)d_in[10];

    float* out = (float*)d_out;

    short* value    = (short*)d_ws;                                  // 16.8 MB
    short* out_part = value + PARTN;                                 // 4 x 16.8 MB
    short* WT_val   = out_part + 4 * PARTN;                          // 128 KB
    short* WT_out   = WT_val + 65536;                                // 128 KB
    short* WT_proj  = WT_out + 65536;                                // 192 KB
    short* proj     = WT_proj + 4 * 96 * 256;                        // 25.2 MB

    // 0) weight prep: fp16, transposed, pre-swizzled
    prep_w<<<896, 256, 0, stream>>>(W_val, W_out, W_off, W_attn, WT_val, WT_out, WT_proj);

    // 1) value projection (fp32 in -> fp16 out)
    gemm_mfma<0, 64, 2, 4, 2><<<dim3(256, 4), 256, 0, stream>>>(
        input_fl, WT_val, b_val, nullptr, value);

    // 2) offset/attn projection (16 GEMMs, fp32 in -> fp16 proj)
    gemm_mfma<2, 96, 1, 2, 6><<<dim3(64, 16), 256, 0, stream>>>(
        seq_query, WT_proj, b_off, b_attn, proj);

    // 3) softmax + bilinear sampling, per-(n,level) XCD pinning (fp16 partials)
    sampler<<<(NB * LEN) / SQB * 4, 256, 0, stream>>>(
        proj, ref_pts, value, out_part);

    // 4) output projection (sum of 4 partials, fp16 in -> fp32 d_out)
    gemm_mfma<4, 64, 2, 4, 2><<<dim3(256, 4), 256, 0, stream>>>(
        out_part, WT_out, b_out, nullptr, out);
}

// Round 15
// 154.225 us; speedup vs baseline: 1.2908x; 1.2908x over previous
//
#include <hip/hip_runtime.h>
#include <math.h>

#define NB   2
#define LVL  4
#define QQ   4096
#define LEN  16384   // LVL*QQ
#define CH   256
#define NH   8
#define DD   32
#define PP   4
#define HL   64
#define WL   64
#define PARTN ((size_t)NB * LEN * CH)   // elements per partial buffer

typedef float    f32x4 __attribute__((ext_vector_type(4)));
typedef _Float16 h16x8 __attribute__((ext_vector_type(8)));
typedef _Float16 h16x2 __attribute__((ext_vector_type(2)));

__device__ __forceinline__ short h2s(_Float16 h) {
    union { _Float16 h; short s; } v; v.h = h; return v.s;
}
__device__ __forceinline__ _Float16 s2h(short s) {
    union { short s; _Float16 h; } v; v.s = s; return v.h;
}
__device__ __forceinline__ h16x2 u2h2(unsigned u) {
    union { unsigned u; h16x2 h; } v; v.u = u; return v.h;
}
__device__ __forceinline__ unsigned h22u(h16x2 h) {
    union { h16x2 h; unsigned u; } v; v.h = h; return v.u;
}

// Convert weights to fp16, transposed to [N][K], 16B-groups XOR-swizzled:
// WT[c][ (g&~7)|((g&7)^(c&7)) *8 + e ] = W[g*8+e][c]
__global__ __launch_bounds__(256) void prep_w(
    const float* __restrict__ W_val, const float* __restrict__ W_out,
    const float* __restrict__ W_off, const float* __restrict__ W_attn,
    short* __restrict__ WT_val, short* __restrict__ WT_out, short* __restrict__ WT_proj)
{
    const int id = blockIdx.x * 256 + threadIdx.x;   // 0 .. 229375
    if (id < 131072) {
        const int which = id >> 16;          // 0: W_val, 1: W_out
        const int u = id & 65535;
        const int c = u >> 8;                // WT row (output col), 0..255
        const int p = u & 255;               // stored position
        const int gp = p >> 3, e = p & 7;
        const int g = (gp & ~7) | ((gp & 7) ^ (c & 7));
        const int k = g * 8 + e;
        const float* W = which ? W_out : W_val;
        short* WT = which ? WT_out : WT_val;
        WT[(size_t)c * 256 + p] = h2s((_Float16)W[(size_t)k * 256 + c]);
    } else {
        const int u = id - 131072;           // 0 .. 98303
        const int i = u / (96 * 256);
        const int r = u % (96 * 256);
        const int c = r >> 8;                // 0..95
        const int p = r & 255;
        const int gp = p >> 3, e = p & 7;
        const int g = (gp & ~7) | ((gp & 7) ^ (c & 7));
        const int k = g * 8 + e;
        float w;
        if (c < 64) w = W_off[((size_t)i * 256 + k) * 64 + c];
        else        w = W_attn[((size_t)i * 256 + k) * 32 + (c - 64)];
        WT_proj[((size_t)i * 96 + c) * 256 + p] = h2s((_Float16)w);
    }
}

// MFMA GEMM (f16): C[M,N] = A[M,256] @ W[256,N] + bias.  BM=128, BK=64.
// MODE 0: A fp32, C fp16 (value proj)
// MODE 2: A fp32 = seq_query[ij], C fp16 proj layout, N=96 (blockIdx.y = ij)
// MODE 4: A = sum of 4 fp16 partials (Ain + k*PARTN), C fp32 (out proj)
template<int MODE, int BN, int WN, int MR, int NR>
__global__ __launch_bounds__(256) void gemm_mfma(
    const void* __restrict__ Ain, const short* __restrict__ WT,
    const float* __restrict__ bias, const float* __restrict__ bias2,
    void* __restrict__ Cout)
{
    __shared__ short sA[128 * 64];     // 16 KB, XOR-swizzled
    __shared__ short sB[BN * 256];     // pre-swizzled rows [col][K]
    const int t    = threadIdx.x;
    const int lane = t & 63;
    const int wave = t >> 6;
    const int m0   = blockIdx.x * 128;

    int i = 0, j = 0, n0 = 0;
    const float* Af = (const float*)Ain;
    const short* Ah = (const short*)Ain;
    const short* wt = WT;
    if (MODE == 2) {
        const int ij = blockIdx.y;
        i = ij >> 2; j = ij & 3;
        Af += (size_t)ij * (NB * QQ) * CH;
        wt += (size_t)i * 96 * 256;
    } else {
        n0 = blockIdx.y * BN;
        wt += (size_t)n0 * 256;
    }

    // stage B once (whole K), linear copy of pre-swizzled rows
    for (int u = t; u < BN * 32; u += 256)
        *(int4*)(sB + (size_t)u * 8) = *(const int4*)(wt + (size_t)u * 8);

    f32x4 acc[MR][NR];
    #pragma unroll
    for (int m = 0; m < MR; ++m)
        #pragma unroll
        for (int n = 0; n < NR; ++n)
            acc[m][n] = (f32x4){0.f, 0.f, 0.f, 0.f};

    const int wr = wave / WN;
    const int wc = wave % WN;
    const int rbase = wr * MR * 16;
    const int cbase = wc * NR * 16;
    const int lr  = lane & 15;
    const int lkg = lane >> 4;

    for (int ko = 0; ko < 4; ++ko) {
        // stage A[128][64] f16 swizzled (fused convert / partial-sum)
        #pragma unroll
        for (int v = 0; v < 4; ++v) {
            const int u = t + v * 256;
            const int row = u >> 3, g = u & 7;
            char* dst = (char*)sA + row * 128 + ((g ^ (row & 7)) << 4);
            const size_t aidx = (size_t)(m0 + row) * CH + ko * 64 + g * 8;
            if (MODE == 4) {
                const h16x8 a0 = *(const h16x8*)(Ah + aidx);
                const h16x8 a1 = *(const h16x8*)(Ah + aidx + PARTN);
                const h16x8 a2 = *(const h16x8*)(Ah + aidx + 2 * PARTN);
                const h16x8 a3 = *(const h16x8*)(Ah + aidx + 3 * PARTN);
                h16x8 w;
                #pragma unroll
                for (int e = 0; e < 8; ++e)
                    w[e] = (_Float16)(((float)a0[e] + (float)a1[e]) +
                                      ((float)a2[e] + (float)a3[e]));
                *(h16x8*)dst = w;
            } else {
                const float* sp = Af + aidx;
                const float4 f0 = *(const float4*)sp;
                const float4 f1 = *(const float4*)(sp + 4);
                h16x8 w;
                w[0] = (_Float16)f0.x; w[1] = (_Float16)f0.y;
                w[2] = (_Float16)f0.z; w[3] = (_Float16)f0.w;
                w[4] = (_Float16)f1.x; w[5] = (_Float16)f1.y;
                w[6] = (_Float16)f1.z; w[7] = (_Float16)f1.w;
                *(h16x8*)dst = w;
            }
        }
        __syncthreads();
        #pragma unroll
        for (int s = 0; s < 2; ++s) {
            h16x8 afr[MR], bfr[NR];
            #pragma unroll
            for (int m = 0; m < MR; ++m) {
                const int row = rbase + m * 16 + lr;
                afr[m] = *(const h16x8*)((const char*)sA + row * 128 +
                                         (((s * 4 + lkg) ^ (row & 7)) << 4));
            }
            #pragma unroll
            for (int n = 0; n < NR; ++n) {
                const int col = cbase + n * 16 + lr;
                const int g  = ko * 8 + s * 4 + lkg;
                const int gp = (g & ~7) | ((g & 7) ^ (col & 7));
                bfr[n] = *(const h16x8*)((const char*)sB + (size_t)col * 512 + (gp << 4));
            }
            #pragma unroll
            for (int m = 0; m < MR; ++m)
                #pragma unroll
                for (int n = 0; n < NR; ++n)
                    acc[m][n] = __builtin_amdgcn_mfma_f32_16x16x32_f16(afr[m], bfr[n], acc[m][n], 0, 0, 0);
        }
        __syncthreads();
    }

    // epilogue: C/D mapping col=lane&15, row=(lane>>4)*4+reg
    #pragma unroll
    for (int m = 0; m < MR; ++m) {
        #pragma unroll
        for (int n = 0; n < NR; ++n) {
            #pragma unroll
            for (int r = 0; r < 4; ++r) {
                const int row = m0 + rbase + m * 16 + (lane >> 4) * 4 + r;
                const int col = cbase + n * 16 + lr;
                const float v = acc[m][n][r];
                if (MODE == 0) {
                    ((short*)Cout)[(size_t)row * CH + n0 + col] = h2s((_Float16)(v + bias[n0 + col]));
                } else if (MODE == 4) {
                    ((float*)Cout)[(size_t)row * CH + n0 + col] = v + bias[n0 + col];
                } else {
                    const int nb = row >> 12, q = row & 4095;
                    const float bc = (col < 64) ? bias[i * 64 + col] : bias2[i * 32 + (col - 64)];
                    ((short*)Cout)[((((size_t)nb * LVL + i) * QQ + q) * LVL + j) * 96 + col] = h2s((_Float16)(v + bc));
                }
            }
        }
    }
}

// Sampler: ONE (n, level) combo per block, combo = bid&7 -> 1:1 with the 8
// XCDs (round-robin dispatch). Each XCD gathers from a 2.1 MB value slice
// that fits its 4 MB L2. 8 queries/block, 2 per wave; writes fp16 partial
// out_part[l]. LDS ~10 KB -> 8 blocks/CU; no VGPR cap (avoid scratch spill).
#define SQB 8
__global__ __launch_bounds__(256) void sampler(
    const short* __restrict__ proj,              // (NB*LEN, 384) fp16
    const float* __restrict__ ref_pts,           // (NB, LEN, LVL, 2)
    const short* __restrict__ value,             // (NB, LEN, 256) fp16
    short* __restrict__ out_part)                // 4 partials of (NB*LEN, 256)
{
    const int bid   = blockIdx.x;
    const int combo = bid & 7;                   // XCD id under %8 round-robin
    const int n     = combo >> 2;                // batch
    const int l     = combo & 3;                 // level
    const int chunk = bid >> 3;                  // 0..2047
    const int iq0   = chunk * SQB;
    const int qf0   = n * LEN + iq0;             // flat query base
    const int t     = threadIdx.x;

    // s_raw[q] (dwords 0..95): [0..31] = my level's offsets (64 shorts),
    //                          [32..95] = attn logits all 4 levels (jj*16+c)
    __shared__ short s_raw[SQB][192];            // 3 KB
    __shared__ float s_ref[SQB][2];              // 64 B
    __shared__ float s_aw [SQB][NH][PP];         // 1 KB
    __shared__ int   s_off[SQB][32][4];          // 4 KB (byte offsets)
    __shared__ short s_wh [SQB][32][4];          // 2 KB (fp16 w*aw)

    // Phase A: stage proj at 64B-line granularity (fully-used lines only)
    for (int u = t; u < SQB * 96; u += 256) {
        const int q = u / 96, w = u % 96;
        const unsigned* row = (const unsigned*)(proj + (size_t)(qf0 + q) * 384);
        unsigned d;
        if (w < 32) d = row[l * 48 + w];                               // offsets
        else        d = row[((w - 32) >> 4) * 48 + 32 + ((w - 32) & 15)]; // attn
        ((unsigned*)&s_raw[q][0])[w] = d;
    }
    if (t < SQB * 2) {
        const int q = t >> 1, xy = t & 1;
        s_ref[q][xy] = ref_pts[((size_t)(qf0 + q) * LVL + l) * 2 + xy];
    }
    __syncthreads();

    // Phase B1: softmax, one thread per (q,h); keep aw of my level
    if (t < SQB * NH) {
        const int q = t >> 3, h = t & 7;
        float lg[16];
        #pragma unroll
        for (int jj = 0; jj < LVL; ++jj)
            #pragma unroll
            for (int p = 0; p < PP; ++p)
                lg[jj * 4 + p] = (float)s2h(s_raw[q][64 + jj * 32 + h * 4 + p]);
        float m = -1e30f;
        #pragma unroll
        for (int e = 0; e < 16; ++e) m = fmaxf(m, lg[e]);
        float s = 0.f;
        #pragma unroll
        for (int e = 0; e < 16; ++e) { lg[e] = __expf(lg[e] - m); s += lg[e]; }
        const float inv = 1.f / s;
        #pragma unroll
        for (int p = 0; p < PP; ++p)
            s_aw[q][h][p] = lg[l * 4 + p] * inv;
    }
    __syncthreads();

    // Phase B2: corner tables, one thread per (q,p,h) = 256 items
    {
        const int q = t >> 5, r = t & 31;
        const int p = (r >> 3) & 3, h = r & 7;
        const float ox = (float)s2h(s_raw[q][h * 8 + p * 2 + 0]);
        const float oy = (float)s2h(s_raw[q][h * 8 + p * 2 + 1]);
        const float aw = s_aw[q][h][p];
        const float px = s_ref[q][0] * (float)WL + ox - 0.5f;
        const float py = s_ref[q][1] * (float)HL + oy - 0.5f;
        const float x0f = floorf(px), y0f = floorf(py);
        const float dx = px - x0f,   dy = py - y0f;
        const int   x0 = (int)x0f,   y0 = (int)y0f;
        #pragma unroll
        for (int c = 0; c < 4; ++c) {
            const int cx = c & 1, cy = c >> 1;
            const int gx = x0 + cx, gy = y0 + cy;
            const bool valid = ((unsigned)gx < (unsigned)WL) && ((unsigned)gy < (unsigned)HL);
            const int cgx = min(max(gx, 0), WL - 1);
            const int cgy = min(max(gy, 0), HL - 1);
            const float w = (cx ? dx : 1.f - dx) * (cy ? dy : 1.f - dy);
            const float wa = valid ? w * aw : 0.f;
            s_off[q][r][c] = (l * QQ + cgy * WL + cgx) * (CH * 2);
            s_wh [q][r][c] = h2s((_Float16)wa);
        }
    }
    __syncthreads();

    // Main: wave = 2 queries; lane = (qsub, h, d8); 8 fp16 channels/thread.
    const int lane = t & 63;
    const int wv   = t >> 6;
    const int q    = wv * 2 + (lane >> 5);
    const int h    = (lane >> 2) & 7;
    const int d8   = lane & 3;
    const unsigned chan = (unsigned)(h * 64 + d8 * 16);  // byte offset of 8 ch
    const char* vb8 = (const char*)(value + (size_t)n * LEN * CH);

    h16x2 acc0 = (h16x2)0, acc1 = (h16x2)0, acc2 = (h16x2)0, acc3 = (h16x2)0;
    {
        uint4 g[16];
        // issue 16 independent gathers
        #pragma unroll
        for (int p = 0; p < PP; ++p) {
            const int r = p * 8 + h;
            const int4 offs = *(const int4*)&s_off[q][r][0];
            g[p * 4 + 0] = *(const uint4*)(vb8 + ((unsigned)offs.x + chan));
            g[p * 4 + 1] = *(const uint4*)(vb8 + ((unsigned)offs.y + chan));
            g[p * 4 + 2] = *(const uint4*)(vb8 + ((unsigned)offs.z + chan));
            g[p * 4 + 3] = *(const uint4*)(vb8 + ((unsigned)offs.w + chan));
        }
        // consume
        #pragma unroll
        for (int p = 0; p < PP; ++p) {
            const int r = p * 8 + h;
            const ushort4 ws = *(const ushort4*)&s_wh[q][r][0];
            #pragma unroll
            for (int c = 0; c < 4; ++c) {
                const unsigned short wu = (c == 0) ? ws.x : (c == 1) ? ws.y : (c == 2) ? ws.z : ws.w;
                h16x2 w; w[0] = s2h((short)wu); w[1] = w[0];
                const uint4 gv = g[p * 4 + c];
                acc0 += w * u2h2(gv.x); acc1 += w * u2h2(gv.y);
                acc2 += w * u2h2(gv.z); acc3 += w * u2h2(gv.w);
            }
        }
    }

    short* outp = out_part + (size_t)l * PARTN;
    uint4 st;
    st.x = h22u(acc0); st.y = h22u(acc1); st.z = h22u(acc2); st.w = h22u(acc3);
    *(uint4*)(outp + (size_t)(qf0 + q) * CH + h * DD + d8 * 8) = st;
}

extern "C" void kernel_launch(void* const* d_in, const int* in_sizes, int n_in,
                              void* d_out, int out_size, void* d_ws, size_t ws_size,
                              hipStream_t stream) {
    const float* seq_query = (const float*)d_in[0];
    const float* ref_pts   = (const float*)d_in[1];
    const float* input_fl  = (const float*)d_in[2];
    const float* W_off     = (const float*)d_in[3];
    const float* b_off     = (const float*)d_in[4];
    const float* W_attn    = (const float*)d_in[5];
    const float* b_attn    = (const float*)d_in[6];
    const float* W_val     = (const float*)d_in[7];
    const float* b_val     = (const float*)d_in[8];
    const float* W_out     = (const float*)d_in[9];
    const float* b_out     = (const float*)d_in[10];

    float* out = (float*)d_out;

    short* value    = (short*)d_ws;                                  // 16.8 MB
    short* out_part = value + PARTN;                                 // 4 x 16.8 MB
    short* WT_val   = out_part + 4 * PARTN;                          // 128 KB
    short* WT_out   = WT_val + 65536;                                // 128 KB
    short* WT_proj  = WT_out + 65536;                                // 192 KB
    short* proj     = WT_proj + 4 * 96 * 256;                        // 25.2 MB

    // 0) weight prep: fp16, transposed, pre-swizzled
    prep_w<<<896, 256, 0, stream>>>(W_val, W_out, W_off, W_attn, WT_val, WT_out, WT_proj);

    // 1) value projection (fp32 in -> fp16 out), BN=128: A read only 2x
    gemm_mfma<0, 128, 2, 4, 4><<<dim3(256, 2), 256, 0, stream>>>(
        input_fl, WT_val, b_val, nullptr, value);

    // 2) offset/attn projection (16 GEMMs, fp32 in -> fp16 proj)
    gemm_mfma<2, 96, 1, 2, 6><<<dim3(64, 16), 256, 0, stream>>>(
        seq_query, WT_proj, b_off, b_attn, proj);

    // 3) softmax + bilinear sampling, per-(n,level) XCD pinning (fp16 partials)
    sampler<<<(NB * LEN) / SQB * 4, 256, 0, stream>>>(
        proj, ref_pts, value, out_part);

    // 4) output projection (sum of 4 partials, fp16 in -> fp32 d_out), BN=128
    gemm_mfma<4, 128, 2, 4, 4><<<dim3(256, 2), 256, 0, stream>>>(
        out_part, WT_out, b_out, nullptr, out);
}

// Round 16
// 152.888 us; speedup vs baseline: 1.3021x; 1.0087x over previous
//
#include <hip/hip_runtime.h>
#include <math.h>

#define NB   2
#define LVL  4
#define QQ   4096
#define LEN  16384   // LVL*QQ
#define CH   256
#define NH   8
#define DD   32
#define PP   4
#define HL   64
#define WL   64
#define PARTN ((size_t)NB * LEN * CH)   // elements per partial buffer

typedef float    f32x4 __attribute__((ext_vector_type(4)));
typedef _Float16 h16x8 __attribute__((ext_vector_type(8)));
typedef _Float16 h16x2 __attribute__((ext_vector_type(2)));

__device__ __forceinline__ short h2s(_Float16 h) {
    union { _Float16 h; short s; } v; v.h = h; return v.s;
}
__device__ __forceinline__ _Float16 s2h(short s) {
    union { short s; _Float16 h; } v; v.s = s; return v.h;
}
__device__ __forceinline__ h16x2 u2h2(unsigned u) {
    union { unsigned u; h16x2 h; } v; v.u = u; return v.h;
}
__device__ __forceinline__ unsigned h22u(h16x2 h) {
    union { h16x2 h; unsigned u; } v; v.h = h; return v.u;
}

// Convert weights to fp16, transposed to [N][K], 16B-groups XOR-swizzled:
// WT[c][ (g&~7)|((g&7)^(c&7)) *8 + e ] = W[g*8+e][c]
__global__ __launch_bounds__(256) void prep_w(
    const float* __restrict__ W_val, const float* __restrict__ W_out,
    const float* __restrict__ W_off, const float* __restrict__ W_attn,
    short* __restrict__ WT_val, short* __restrict__ WT_out, short* __restrict__ WT_proj)
{
    const int id = blockIdx.x * 256 + threadIdx.x;   // 0 .. 229375
    if (id < 131072) {
        const int which = id >> 16;          // 0: W_val, 1: W_out
        const int u = id & 65535;
        const int c = u >> 8;                // WT row (output col), 0..255
        const int p = u & 255;               // stored position
        const int gp = p >> 3, e = p & 7;
        const int g = (gp & ~7) | ((gp & 7) ^ (c & 7));
        const int k = g * 8 + e;
        const float* W = which ? W_out : W_val;
        short* WT = which ? WT_out : WT_val;
        WT[(size_t)c * 256 + p] = h2s((_Float16)W[(size_t)k * 256 + c]);
    } else {
        const int u = id - 131072;           // 0 .. 98303
        const int i = u / (96 * 256);
        const int r = u % (96 * 256);
        const int c = r >> 8;                // 0..95
        const int p = r & 255;
        const int gp = p >> 3, e = p & 7;
        const int g = (gp & ~7) | ((gp & 7) ^ (c & 7));
        const int k = g * 8 + e;
        float w;
        if (c < 64) w = W_off[((size_t)i * 256 + k) * 64 + c];
        else        w = W_attn[((size_t)i * 256 + k) * 32 + (c - 64)];
        WT_proj[((size_t)i * 96 + c) * 256 + p] = h2s((_Float16)w);
    }
}

// MFMA GEMM (f16): C[M,N] = A[M,256] @ W[256,N] + bias.  BM=128, BK=64.
// MODE 0: A fp32, C fp16 (value proj)
// MODE 2: A fp32 = seq_query[ij], C fp16 proj layout, N=96 (blockIdx.y = ij)
// MODE 4: A = sum of 4 fp16 partials (Ain + k*PARTN), C fp32 (out proj)
template<int MODE, int BN, int WN, int MR, int NR, int TPB = 256>
__global__ __launch_bounds__(TPB) void gemm_mfma(
    const void* __restrict__ Ain, const short* __restrict__ WT,
    const float* __restrict__ bias, const float* __restrict__ bias2,
    void* __restrict__ Cout)
{
    __shared__ short sA[128 * 64];     // 16 KB, XOR-swizzled
    __shared__ short sB[BN * 256];     // pre-swizzled rows [col][K]
    const int t    = threadIdx.x;
    const int lane = t & 63;
    const int wave = t >> 6;
    const int m0   = blockIdx.x * 128;

    int i = 0, j = 0, n0 = 0;
    const float* Af = (const float*)Ain;
    const short* Ah = (const short*)Ain;
    const short* wt = WT;
    if (MODE == 2) {
        const int ij = blockIdx.y;
        i = ij >> 2; j = ij & 3;
        Af += (size_t)ij * (NB * QQ) * CH;
        wt += (size_t)i * 96 * 256;
    } else {
        n0 = blockIdx.y * BN;
        wt += (size_t)n0 * 256;
    }

    // stage B once (whole K), linear copy of pre-swizzled rows
    for (int u = t; u < BN * 32; u += TPB)
        *(int4*)(sB + (size_t)u * 8) = *(const int4*)(wt + (size_t)u * 8);

    f32x4 acc[MR][NR];
    #pragma unroll
    for (int m = 0; m < MR; ++m)
        #pragma unroll
        for (int n = 0; n < NR; ++n)
            acc[m][n] = (f32x4){0.f, 0.f, 0.f, 0.f};

    const int wr = wave / WN;
    const int wc = wave % WN;
    const int rbase = wr * MR * 16;
    const int cbase = wc * NR * 16;
    const int lr  = lane & 15;
    const int lkg = lane >> 4;

    for (int ko = 0; ko < 4; ++ko) {
        // stage A[128][64] f16 swizzled (fused convert / partial-sum)
        #pragma unroll
        for (int v = 0; v < 1024 / TPB; ++v) {
            const int u = t + v * TPB;
            const int row = u >> 3, g = u & 7;
            char* dst = (char*)sA + row * 128 + ((g ^ (row & 7)) << 4);
            const size_t aidx = (size_t)(m0 + row) * CH + ko * 64 + g * 8;
            if (MODE == 4) {
                const h16x8 a0 = *(const h16x8*)(Ah + aidx);
                const h16x8 a1 = *(const h16x8*)(Ah + aidx + PARTN);
                const h16x8 a2 = *(const h16x8*)(Ah + aidx + 2 * PARTN);
                const h16x8 a3 = *(const h16x8*)(Ah + aidx + 3 * PARTN);
                h16x8 w;
                #pragma unroll
                for (int e = 0; e < 8; ++e)
                    w[e] = (_Float16)(((float)a0[e] + (float)a1[e]) +
                                      ((float)a2[e] + (float)a3[e]));
                *(h16x8*)dst = w;
            } else {
                const float* sp = Af + aidx;
                const float4 f0 = *(const float4*)sp;
                const float4 f1 = *(const float4*)(sp + 4);
                h16x8 w;
                w[0] = (_Float16)f0.x; w[1] = (_Float16)f0.y;
                w[2] = (_Float16)f0.z; w[3] = (_Float16)f0.w;
                w[4] = (_Float16)f1.x; w[5] = (_Float16)f1.y;
                w[6] = (_Float16)f1.z; w[7] = (_Float16)f1.w;
                *(h16x8*)dst = w;
            }
        }
        __syncthreads();
        #pragma unroll
        for (int s = 0; s < 2; ++s) {
            h16x8 afr[MR], bfr[NR];
            #pragma unroll
            for (int m = 0; m < MR; ++m) {
                const int row = rbase + m * 16 + lr;
                afr[m] = *(const h16x8*)((const char*)sA + row * 128 +
                                         (((s * 4 + lkg) ^ (row & 7)) << 4));
            }
            #pragma unroll
            for (int n = 0; n < NR; ++n) {
                const int col = cbase + n * 16 + lr;
                const int g  = ko * 8 + s * 4 + lkg;
                const int gp = (g & ~7) | ((g & 7) ^ (col & 7));
                bfr[n] = *(const h16x8*)((const char*)sB + (size_t)col * 512 + (gp << 4));
            }
            #pragma unroll
            for (int m = 0; m < MR; ++m)
                #pragma unroll
                for (int n = 0; n < NR; ++n)
                    acc[m][n] = __builtin_amdgcn_mfma_f32_16x16x32_f16(afr[m], bfr[n], acc[m][n], 0, 0, 0);
        }
        __syncthreads();
    }

    // epilogue: C/D mapping col=lane&15, row=(lane>>4)*4+reg
    #pragma unroll
    for (int m = 0; m < MR; ++m) {
        #pragma unroll
        for (int n = 0; n < NR; ++n) {
            #pragma unroll
            for (int r = 0; r < 4; ++r) {
                const int row = m0 + rbase + m * 16 + (lane >> 4) * 4 + r;
                const int col = cbase + n * 16 + lr;
                const float v = acc[m][n][r];
                if (MODE == 0) {
                    ((short*)Cout)[(size_t)row * CH + n0 + col] = h2s((_Float16)(v + bias[n0 + col]));
                } else if (MODE == 4) {
                    ((float*)Cout)[(size_t)row * CH + n0 + col] = v + bias[n0 + col];
                } else {
                    const int nb = row >> 12, q = row & 4095;
                    const float bc = (col < 64) ? bias[i * 64 + col] : bias2[i * 32 + (col - 64)];
                    ((short*)Cout)[((((size_t)nb * LVL + i) * QQ + q) * LVL + j) * 96 + col] = h2s((_Float16)(v + bc));
                }
            }
        }
    }
}

// Sampler: ONE (n, level) combo per block, combo = bid&7 -> 1:1 with the 8
// XCDs (round-robin dispatch). Each XCD gathers from a 2.1 MB value slice
// that fits its 4 MB L2. 8 queries/block, 2 per wave; writes fp16 partial
// out_part[l]. LDS ~10 KB -> 8 blocks/CU; no VGPR cap (avoid scratch spill).
#define SQB 8
__global__ __launch_bounds__(256) void sampler(
    const short* __restrict__ proj,              // (NB*LEN, 384) fp16
    const float* __restrict__ ref_pts,           // (NB, LEN, LVL, 2)
    const short* __restrict__ value,             // (NB, LEN, 256) fp16
    short* __restrict__ out_part)                // 4 partials of (NB*LEN, 256)
{
    const int bid   = blockIdx.x;
    const int combo = bid & 7;                   // XCD id under %8 round-robin
    const int n     = combo >> 2;                // batch
    const int l     = combo & 3;                 // level
    const int chunk = bid >> 3;                  // 0..2047
    const int iq0   = chunk * SQB;
    const int qf0   = n * LEN + iq0;             // flat query base
    const int t     = threadIdx.x;

    // s_raw[q] (dwords 0..95): [0..31] = my level's offsets (64 shorts),
    //                          [32..95] = attn logits all 4 levels (jj*16+c)
    __shared__ short s_raw[SQB][192];            // 3 KB
    __shared__ float s_ref[SQB][2];              // 64 B
    __shared__ float s_aw [SQB][NH][PP];         // 1 KB
    __shared__ int   s_off[SQB][32][4];          // 4 KB (byte offsets)
    __shared__ short s_wh [SQB][32][4];          // 2 KB (fp16 w*aw)

    // Phase A: stage proj at 64B-line granularity (fully-used lines only)
    for (int u = t; u < SQB * 96; u += 256) {
        const int q = u / 96, w = u % 96;
        const unsigned* row = (const unsigned*)(proj + (size_t)(qf0 + q) * 384);
        unsigned d;
        if (w < 32) d = row[l * 48 + w];                               // offsets
        else        d = row[((w - 32) >> 4) * 48 + 32 + ((w - 32) & 15)]; // attn
        ((unsigned*)&s_raw[q][0])[w] = d;
    }
    if (t < SQB * 2) {
        const int q = t >> 1, xy = t & 1;
        s_ref[q][xy] = ref_pts[((size_t)(qf0 + q) * LVL + l) * 2 + xy];
    }
    __syncthreads();

    // Phase B1: softmax, one thread per (q,h); keep aw of my level
    if (t < SQB * NH) {
        const int q = t >> 3, h = t & 7;
        float lg[16];
        #pragma unroll
        for (int jj = 0; jj < LVL; ++jj)
            #pragma unroll
            for (int p = 0; p < PP; ++p)
                lg[jj * 4 + p] = (float)s2h(s_raw[q][64 + jj * 32 + h * 4 + p]);
        float m = -1e30f;
        #pragma unroll
        for (int e = 0; e < 16; ++e) m = fmaxf(m, lg[e]);
        float s = 0.f;
        #pragma unroll
        for (int e = 0; e < 16; ++e) { lg[e] = __expf(lg[e] - m); s += lg[e]; }
        const float inv = 1.f / s;
        #pragma unroll
        for (int p = 0; p < PP; ++p)
            s_aw[q][h][p] = lg[l * 4 + p] * inv;
    }
    __syncthreads();

    // Phase B2: corner tables, one thread per (q,p,h) = 256 items
    {
        const int q = t >> 5, r = t & 31;
        const int p = (r >> 3) & 3, h = r & 7;
        const float ox = (float)s2h(s_raw[q][h * 8 + p * 2 + 0]);
        const float oy = (float)s2h(s_raw[q][h * 8 + p * 2 + 1]);
        const float aw = s_aw[q][h][p];
        const float px = s_ref[q][0] * (float)WL + ox - 0.5f;
        const float py = s_ref[q][1] * (float)HL + oy - 0.5f;
        const float x0f = floorf(px), y0f = floorf(py);
        const float dx = px - x0f,   dy = py - y0f;
        const int   x0 = (int)x0f,   y0 = (int)y0f;
        #pragma unroll
        for (int c = 0; c < 4; ++c) {
            const int cx = c & 1, cy = c >> 1;
            const int gx = x0 + cx, gy = y0 + cy;
            const bool valid = ((unsigned)gx < (unsigned)WL) && ((unsigned)gy < (unsigned)HL);
            const int cgx = min(max(gx, 0), WL - 1);
            const int cgy = min(max(gy, 0), HL - 1);
            const float w = (cx ? dx : 1.f - dx) * (cy ? dy : 1.f - dy);
            const float wa = valid ? w * aw : 0.f;
            s_off[q][r][c] = (l * QQ + cgy * WL + cgx) * (CH * 2);
            s_wh [q][r][c] = h2s((_Float16)wa);
        }
    }
    __syncthreads();

    // Main: wave = 2 queries; lane = (qsub, h, d8); 8 fp16 channels/thread.
    const int lane = t & 63;
    const int wv   = t >> 6;
    const int q    = wv * 2 + (lane >> 5);
    const int h    = (lane >> 2) & 7;
    const int d8   = lane & 3;
    const unsigned chan = (unsigned)(h * 64 + d8 * 16);  // byte offset of 8 ch
    const char* vb8 = (const char*)(value + (size_t)n * LEN * CH);

    h16x2 acc0 = (h16x2)0, acc1 = (h16x2)0, acc2 = (h16x2)0, acc3 = (h16x2)0;
    {
        uint4 g[16];
        // issue 16 independent gathers
        #pragma unroll
        for (int p = 0; p < PP; ++p) {
            const int r = p * 8 + h;
            const int4 offs = *(const int4*)&s_off[q][r][0];
            g[p * 4 + 0] = *(const uint4*)(vb8 + ((unsigned)offs.x + chan));
            g[p * 4 + 1] = *(const uint4*)(vb8 + ((unsigned)offs.y + chan));
            g[p * 4 + 2] = *(const uint4*)(vb8 + ((unsigned)offs.z + chan));
            g[p * 4 + 3] = *(const uint4*)(vb8 + ((unsigned)offs.w + chan));
        }
        // consume
        #pragma unroll
        for (int p = 0; p < PP; ++p) {
            const int r = p * 8 + h;
            const ushort4 ws = *(const ushort4*)&s_wh[q][r][0];
            #pragma unroll
            for (int c = 0; c < 4; ++c) {
                const unsigned short wu = (c == 0) ? ws.x : (c == 1) ? ws.y : (c == 2) ? ws.z : ws.w;
                h16x2 w; w[0] = s2h((short)wu); w[1] = w[0];
                const uint4 gv = g[p * 4 + c];
                acc0 += w * u2h2(gv.x); acc1 += w * u2h2(gv.y);
                acc2 += w * u2h2(gv.z); acc3 += w * u2h2(gv.w);
            }
        }
    }

    short* outp = out_part + (size_t)l * PARTN;
    uint4 st;
    st.x = h22u(acc0); st.y = h22u(acc1); st.z = h22u(acc2); st.w = h22u(acc3);
    *(uint4*)(outp + (size_t)(qf0 + q) * CH + h * DD + d8 * 8) = st;
}

extern "C" void kernel_launch(void* const* d_in, const int* in_sizes, int n_in,
                              void* d_out, int out_size, void* d_ws, size_t ws_size,
                              hipStream_t stream) {
    const float* seq_query = (const float*)d_in[0];
    const float* ref_pts   = (const float*)d_in[1];
    const float* input_fl  = (const float*)d_in[2];
    const float* W_off     = (const float*)d_in[3];
    const float* b_off     = (const float*)d_in[4];
    const float* W_attn    = (const float*)d_in[5];
    const float* b_attn    = (const float*)d_in[6];
    const float* W_val     = (const float*)d_in[7];
    const float* b_val     = (const float*)d_in[8];
    const float* W_out     = (const float*)d_in[9];
    const float* b_out     = (const float*)d_in[10];

    float* out = (float*)d_out;

    short* value    = (short*)d_ws;                                  // 16.8 MB
    short* out_part = value + PARTN;                                 // 4 x 16.8 MB
    short* WT_val   = out_part + 4 * PARTN;                          // 128 KB
    short* WT_out   = WT_val + 65536;                                // 128 KB
    short* WT_proj  = WT_out + 65536;                                // 192 KB
    short* proj     = WT_proj + 4 * 96 * 256;                        // 25.2 MB

    // 0) weight prep: fp16, transposed, pre-swizzled
    prep_w<<<896, 256, 0, stream>>>(W_val, W_out, W_off, W_attn, WT_val, WT_out, WT_proj);

    // 1) value projection (fp32 in -> fp16 out), BN=256: A read exactly once
    gemm_mfma<0, 256, 4, 4, 4, 512><<<dim3(256, 1), 512, 0, stream>>>(
        input_fl, WT_val, b_val, nullptr, value);

    // 2) offset/attn projection (16 GEMMs, fp32 in -> fp16 proj)
    gemm_mfma<2, 96, 1, 2, 6><<<dim3(64, 16), 256, 0, stream>>>(
        seq_query, WT_proj, b_off, b_attn, proj);

    // 3) softmax + bilinear sampling, per-(n,level) XCD pinning (fp16 partials)
    sampler<<<(NB * LEN) / SQB * 4, 256, 0, stream>>>(
        proj, ref_pts, value, out_part);

    // 4) output projection (sum of 4 partials, fp16 in -> fp32 d_out), BN=256
    gemm_mfma<4, 256, 4, 4, 4, 512><<<dim3(256, 1), 512, 0, stream>>>(
        out_part, WT_out, b_out, nullptr, out);
}

// Round 17
// 152.625 us; speedup vs baseline: 1.3043x; 1.0017x over previous
//
#include <hip/hip_runtime.h>
#include <math.h>

#define NB   2
#define LVL  4
#define QQ   4096
#define LEN  16384   // LVL*QQ
#define CH   256
#define NH   8
#define DD   32
#define PP   4
#define HL   64
#define WL   64
#define PARTN ((size_t)NB * LEN * CH)   // elements per partial buffer
#define V2PIX 512                        // shorts per pixel in value2: [NH][2][DD]

typedef float    f32x4 __attribute__((ext_vector_type(4)));
typedef _Float16 h16x8 __attribute__((ext_vector_type(8)));
typedef _Float16 h16x2 __attribute__((ext_vector_type(2)));

__device__ __forceinline__ short h2s(_Float16 h) {
    union { _Float16 h; short s; } v; v.h = h; return v.s;
}
__device__ __forceinline__ _Float16 s2h(short s) {
    union { short s; _Float16 h; } v; v.s = s; return v.h;
}
__device__ __forceinline__ h16x2 u2h2(unsigned u) {
    union { unsigned u; h16x2 h; } v; v.u = u; return v.h;
}
__device__ __forceinline__ unsigned h22u(h16x2 h) {
    union { h16x2 h; unsigned u; } v; v.h = h; return v.u;
}

// Convert weights to fp16, transposed to [N][K], 16B-groups XOR-swizzled:
// WT[c][ (g&~7)|((g&7)^(c&7)) *8 + e ] = W[g*8+e][c]
__global__ __launch_bounds__(256) void prep_w(
    const float* __restrict__ W_val, const float* __restrict__ W_out,
    const float* __restrict__ W_off, const float* __restrict__ W_attn,
    short* __restrict__ WT_val, short* __restrict__ WT_out, short* __restrict__ WT_proj)
{
    const int id = blockIdx.x * 256 + threadIdx.x;   // 0 .. 229375
    if (id < 131072) {
        const int which = id >> 16;          // 0: W_val, 1: W_out
        const int u = id & 65535;
        const int c = u >> 8;                // WT row (output col), 0..255
        const int p = u & 255;               // stored position
        const int gp = p >> 3, e = p & 7;
        const int g = (gp & ~7) | ((gp & 7) ^ (c & 7));
        const int k = g * 8 + e;
        const float* W = which ? W_out : W_val;
        short* WT = which ? WT_out : WT_val;
        WT[(size_t)c * 256 + p] = h2s((_Float16)W[(size_t)k * 256 + c]);
    } else {
        const int u = id - 131072;           // 0 .. 98303
        const int i = u / (96 * 256);
        const int r = u % (96 * 256);
        const int c = r >> 8;                // 0..95
        const int p = r & 255;
        const int gp = p >> 3, e = p & 7;
        const int g = (gp & ~7) | ((gp & 7) ^ (c & 7));
        const int k = g * 8 + e;
        float w;
        if (c < 64) w = W_off[((size_t)i * 256 + k) * 64 + c];
        else        w = W_attn[((size_t)i * 256 + k) * 32 + (c - 64)];
        WT_proj[((size_t)i * 96 + c) * 256 + p] = h2s((_Float16)w);
    }
}

// MFMA GEMM (f16): C[M,N] = A[M,256] @ W[256,N] + bias.  BM=128, BK=64.
// MODE 0: A fp32, C fp16 written to value2 paired layout (value proj)
// MODE 2: A fp32 = seq_query[ij], C fp16 proj layout, N=96 (blockIdx.y = ij)
// MODE 4: A = sum of 4 fp16 partials (Ain + k*PARTN), C fp32 (out proj)
template<int MODE, int BN, int WN, int MR, int NR, int TPB = 256>
__global__ __launch_bounds__(TPB) void gemm_mfma(
    const void* __restrict__ Ain, const short* __restrict__ WT,
    const float* __restrict__ bias, const float* __restrict__ bias2,
    void* __restrict__ Cout)
{
    __shared__ short sA[128 * 64];     // 16 KB, XOR-swizzled
    __shared__ short sB[BN * 256];     // pre-swizzled rows [col][K]
    const int t    = threadIdx.x;
    const int lane = t & 63;
    const int wave = t >> 6;
    const int m0   = blockIdx.x * 128;

    int i = 0, j = 0, n0 = 0;
    const float* Af = (const float*)Ain;
    const short* Ah = (const short*)Ain;
    const short* wt = WT;
    if (MODE == 2) {
        const int ij = blockIdx.y;
        i = ij >> 2; j = ij & 3;
        Af += (size_t)ij * (NB * QQ) * CH;
        wt += (size_t)i * 96 * 256;
    } else {
        n0 = blockIdx.y * BN;
        wt += (size_t)n0 * 256;
    }

    // stage B once (whole K), linear copy of pre-swizzled rows
    for (int u = t; u < BN * 32; u += TPB)
        *(int4*)(sB + (size_t)u * 8) = *(const int4*)(wt + (size_t)u * 8);

    f32x4 acc[MR][NR];
    #pragma unroll
    for (int m = 0; m < MR; ++m)
        #pragma unroll
        for (int n = 0; n < NR; ++n)
            acc[m][n] = (f32x4){0.f, 0.f, 0.f, 0.f};

    const int wr = wave / WN;
    const int wc = wave % WN;
    const int rbase = wr * MR * 16;
    const int cbase = wc * NR * 16;
    const int lr  = lane & 15;
    const int lkg = lane >> 4;

    for (int ko = 0; ko < 4; ++ko) {
        // stage A[128][64] f16 swizzled (fused convert / partial-sum)
        #pragma unroll
        for (int v = 0; v < 1024 / TPB; ++v) {
            const int u = t + v * TPB;
            const int row = u >> 3, g = u & 7;
            char* dst = (char*)sA + row * 128 + ((g ^ (row & 7)) << 4);
            const size_t aidx = (size_t)(m0 + row) * CH + ko * 64 + g * 8;
            if (MODE == 4) {
                const h16x8 a0 = *(const h16x8*)(Ah + aidx);
                const h16x8 a1 = *(const h16x8*)(Ah + aidx + PARTN);
                const h16x8 a2 = *(const h16x8*)(Ah + aidx + 2 * PARTN);
                const h16x8 a3 = *(const h16x8*)(Ah + aidx + 3 * PARTN);
                h16x8 w;
                #pragma unroll
                for (int e = 0; e < 8; ++e)
                    w[e] = (_Float16)(((float)a0[e] + (float)a1[e]) +
                                      ((float)a2[e] + (float)a3[e]));
                *(h16x8*)dst = w;
            } else {
                const float* sp = Af + aidx;
                const float4 f0 = *(const float4*)sp;
                const float4 f1 = *(const float4*)(sp + 4);
                h16x8 w;
                w[0] = (_Float16)f0.x; w[1] = (_Float16)f0.y;
                w[2] = (_Float16)f0.z; w[3] = (_Float16)f0.w;
                w[4] = (_Float16)f1.x; w[5] = (_Float16)f1.y;
                w[6] = (_Float16)f1.z; w[7] = (_Float16)f1.w;
                *(h16x8*)dst = w;
            }
        }
        __syncthreads();
        #pragma unroll
        for (int s = 0; s < 2; ++s) {
            h16x8 afr[MR], bfr[NR];
            #pragma unroll
            for (int m = 0; m < MR; ++m) {
                const int row = rbase + m * 16 + lr;
                afr[m] = *(const h16x8*)((const char*)sA + row * 128 +
                                         (((s * 4 + lkg) ^ (row & 7)) << 4));
            }
            #pragma unroll
            for (int n = 0; n < NR; ++n) {
                const int col = cbase + n * 16 + lr;
                const int g  = ko * 8 + s * 4 + lkg;
                const int gp = (g & ~7) | ((g & 7) ^ (col & 7));
                bfr[n] = *(const h16x8*)((const char*)sB + (size_t)col * 512 + (gp << 4));
            }
            #pragma unroll
            for (int m = 0; m < MR; ++m)
                #pragma unroll
                for (int n = 0; n < NR; ++n)
                    acc[m][n] = __builtin_amdgcn_mfma_f32_16x16x32_f16(afr[m], bfr[n], acc[m][n], 0, 0, 0);
        }
        __syncthreads();
    }

    // epilogue: C/D mapping col=lane&15, row=(lane>>4)*4+reg
    #pragma unroll
    for (int m = 0; m < MR; ++m) {
        #pragma unroll
        for (int n = 0; n < NR; ++n) {
            #pragma unroll
            for (int r = 0; r < 4; ++r) {
                const int row = m0 + rbase + m * 16 + (lane >> 4) * 4 + r;
                const int col = cbase + n * 16 + lr;
                const float v = acc[m][n][r];
                if (MODE == 0) {
                    // value2 paired layout: [pixel][h][pair][d]
                    const int c  = n0 + col;
                    const int hh = c >> 5, dd = c & 31;
                    const short hv = h2s((_Float16)(v + bias[c]));
                    short* v2 = (short*)Cout;
                    v2[(size_t)row * V2PIX + hh * 64 + dd] = hv;          // own pair0
                    if ((row & 63) != 0)                                   // left nbr pair1
                        v2[(size_t)(row - 1) * V2PIX + hh * 64 + 32 + dd] = hv;
                } else if (MODE == 4) {
                    ((float*)Cout)[(size_t)row * CH + n0 + col] = v + bias[n0 + col];
                } else {
                    const int nb = row >> 12, q = row & 4095;
                    const float bc = (col < 64) ? bias[i * 64 + col] : bias2[i * 32 + (col - 64)];
                    ((short*)Cout)[((((size_t)nb * LVL + i) * QQ + q) * LVL + j) * 96 + col] = h2s((_Float16)(v + bc));
                }
            }
        }
    }
}

// Sampler: one (n,level) per block (combo = bid&7 -> XCD-pinned; 2.1->4.2MB
// value2 slice). Paired-pixel gathers: lane = (h, pair, d8); per (q,p,ycorner)
// all 8 heads fetch one 128B span covering BOTH x-corners -> half the L2
// requests of the 64B scheme. Pair-sum via shfl_xor(4) in fp16.
#define SQB 8
__global__ __launch_bounds__(256) void sampler(
    const short* __restrict__ proj,              // (NB*LEN, 384) fp16
    const float* __restrict__ ref_pts,           // (NB, LEN, LVL, 2)
    const short* __restrict__ value2,            // (NB, LEN, NH, 2, DD) fp16
    short* __restrict__ out_part)                // 4 partials of (NB*LEN, 256)
{
    const int bid   = blockIdx.x;
    const int combo = bid & 7;                   // XCD id under %8 round-robin
    const int n     = combo >> 2;                // batch
    const int l     = combo & 3;                 // level
    const int chunk = bid >> 3;                  // 0..2047
    const int iq0   = chunk * SQB;
    const int qf0   = n * LEN + iq0;             // flat query base
    const int t     = threadIdx.x;

    // s_raw[q]: shorts 0..63 = my level's offsets, 64..191 = attn logits (all lv)
    __shared__ short    s_raw[SQB][192];         // 3 KB
    __shared__ float    s_ref[SQB][2];           // 64 B
    __shared__ float    s_aw [SQB][NH][PP];      // 1 KB
    __shared__ int      s_off[SQB][32][2];       // 2 KB (row byte offsets y0,y1)
    __shared__ unsigned s_w  [SQB][32][2];       // 2 KB (per pair: packed y0,y1 w)

    // Phase A: stage proj at 64B-line granularity (fully-used lines only)
    for (int u = t; u < SQB * 96; u += 256) {
        const int q = u / 96, w = u % 96;
        const unsigned* row = (const unsigned*)(proj + (size_t)(qf0 + q) * 384);
        unsigned d;
        if (w < 32) d = row[l * 48 + w];                                  // offsets
        else        d = row[((w - 32) >> 4) * 48 + 32 + ((w - 32) & 15)]; // attn
        ((unsigned*)&s_raw[q][0])[w] = d;
    }
    if (t < SQB * 2) {
        const int q = t >> 1, xy = t & 1;
        s_ref[q][xy] = ref_pts[((size_t)(qf0 + q) * LVL + l) * 2 + xy];
    }
    __syncthreads();

    // Phase B1: softmax, one thread per (q,h); keep aw of my level
    if (t < SQB * NH) {
        const int q = t >> 3, h = t & 7;
        float lg[16];
        #pragma unroll
        for (int jj = 0; jj < LVL; ++jj)
            #pragma unroll
            for (int p = 0; p < PP; ++p)
                lg[jj * 4 + p] = (float)s2h(s_raw[q][64 + jj * 32 + h * 4 + p]);
        float m = -1e30f;
        #pragma unroll
        for (int e = 0; e < 16; ++e) m = fmaxf(m, lg[e]);
        float s = 0.f;
        #pragma unroll
        for (int e = 0; e < 16; ++e) { lg[e] = __expf(lg[e] - m); s += lg[e]; }
        const float inv = 1.f / s;
        #pragma unroll
        for (int p = 0; p < PP; ++p)
            s_aw[q][h][p] = lg[l * 4 + p] * inv;
    }
    __syncthreads();

    // Phase B2: corner tables, one thread per (q,p,h) = 256 items
    {
        const int q = t >> 5, r = t & 31;
        const int p = (r >> 3) & 3, h = r & 7;
        const float ox = (float)s2h(s_raw[q][h * 8 + p * 2 + 0]);
        const float oy = (float)s2h(s_raw[q][h * 8 + p * 2 + 1]);
        const float aw = s_aw[q][h][p];
        const float px = s_ref[q][0] * (float)WL + ox - 0.5f;
        const float py = s_ref[q][1] * (float)HL + oy - 0.5f;
        const float x0f = floorf(px), y0f = floorf(py);
        const float dx = px - x0f,   dy = py - y0f;
        const int   x0 = (int)x0f,   y0 = (int)y0f;

        const int bx = min(max(x0, 0), WL - 2);    // base pixel (covers x0,x0+1)
        float wx[2];
        #pragma unroll
        for (int k = 0; k < 2; ++k) {
            const int xx = bx + k;
            float w = 0.f;
            if (xx == x0 && (unsigned)x0 < (unsigned)WL)           w = 1.f - dx;
            else if (xx == x0 + 1 && (unsigned)(x0 + 1) < (unsigned)WL) w = dx;
            wx[k] = w;
        }
        float wy[2];
        int   cy[2];
        #pragma unroll
        for (int yc = 0; yc < 2; ++yc) {
            const int gy = y0 + yc;
            const bool vy = (unsigned)gy < (unsigned)HL;
            cy[yc] = min(max(gy, 0), HL - 1);
            wy[yc] = vy ? (yc ? dy : 1.f - dy) : 0.f;
        }
        #pragma unroll
        for (int yc = 0; yc < 2; ++yc)
            s_off[q][r][yc] = (l * QQ + cy[yc] * WL + bx) * (V2PIX * 2);
        #pragma unroll
        for (int k = 0; k < 2; ++k) {
            h16x2 wv;
            wv[0] = (_Float16)(wy[0] * wx[k] * aw);
            wv[1] = (_Float16)(wy[1] * wx[k] * aw);
            s_w[q][r][k] = h22u(wv);
        }
    }
    __syncthreads();

    // Main: wave handles 2 queries sequentially; lane = (h, pair, d8).
    const int lane  = t & 63;
    const int wv    = t >> 6;
    const int h     = lane >> 3;
    const int pairr = (lane >> 2) & 1;
    const int d8    = lane & 3;
    const unsigned chan = (unsigned)(h * 128 + pairr * 64 + d8 * 16);
    const char* vb8 = (const char*)value2 + (size_t)n * LEN * (V2PIX * 2);
    short* outp = out_part + (size_t)l * PARTN;

    #pragma unroll
    for (int sub = 0; sub < 2; ++sub) {
        const int q = wv * 2 + sub;
        uint4 g[8];
        // issue 8 independent 128B-span gathers (one per p,ycorner)
        #pragma unroll
        for (int p = 0; p < PP; ++p) {
            const int2 offs = *(const int2*)&s_off[q][p * 8 + h][0];
            g[p * 2 + 0] = *(const uint4*)(vb8 + ((unsigned)offs.x + chan));
            g[p * 2 + 1] = *(const uint4*)(vb8 + ((unsigned)offs.y + chan));
        }
        // consume
        h16x2 a0 = (h16x2)0, a1 = (h16x2)0, a2 = (h16x2)0, a3 = (h16x2)0;
        #pragma unroll
        for (int p = 0; p < PP; ++p) {
            const h16x2 wp = u2h2(s_w[q][p * 8 + h][pairr]);
            h16x2 w0; w0[0] = wp[0]; w0[1] = wp[0];
            h16x2 w1; w1[0] = wp[1]; w1[1] = wp[1];
            {
                const uint4 gv = g[p * 2 + 0];
                a0 += w0 * u2h2(gv.x); a1 += w0 * u2h2(gv.y);
                a2 += w0 * u2h2(gv.z); a3 += w0 * u2h2(gv.w);
            }
            {
                const uint4 gv = g[p * 2 + 1];
                a0 += w1 * u2h2(gv.x); a1 += w1 * u2h2(gv.y);
                a2 += w1 * u2h2(gv.z); a3 += w1 * u2h2(gv.w);
            }
        }
        // pair reduce: lane(pair0) += lane(pair1)
        a0 += u2h2((unsigned)__shfl_xor((int)h22u(a0), 4, 64));
        a1 += u2h2((unsigned)__shfl_xor((int)h22u(a1), 4, 64));
        a2 += u2h2((unsigned)__shfl_xor((int)h22u(a2), 4, 64));
        a3 += u2h2((unsigned)__shfl_xor((int)h22u(a3), 4, 64));
        if (pairr == 0) {
            uint4 st;
            st.x = h22u(a0); st.y = h22u(a1); st.z = h22u(a2); st.w = h22u(a3);
            *(uint4*)(outp + (size_t)(qf0 + q) * CH + h * DD + d8 * 8) = st;
        }
    }
}

extern "C" void kernel_launch(void* const* d_in, const int* in_sizes, int n_in,
                              void* d_out, int out_size, void* d_ws, size_t ws_size,
                              hipStream_t stream) {
    const float* seq_query = (const float*)d_in[0];
    const float* ref_pts   = (const float*)d_in[1];
    const float* input_fl  = (const float*)d_in[2];
    const float* W_off     = (const float*)d_in[3];
    const float* b_off     = (const float*)d_in[4];
    const float* W_attn    = (const float*)d_in[5];
    const float* b_attn    = (const float*)d_in[6];
    const float* W_val     = (const float*)d_in[7];
    const float* b_val     = (const float*)d_in[8];
    const float* W_out     = (const float*)d_in[9];
    const float* b_out     = (const float*)d_in[10];

    float* out = (float*)d_out;

    short* value2   = (short*)d_ws;                                  // 33.5 MB
    short* out_part = value2 + (size_t)NB * LEN * V2PIX;             // 4 x 16.8 MB
    short* WT_val   = out_part + 4 * PARTN;                          // 128 KB
    short* WT_out   = WT_val + 65536;                                // 128 KB
    short* WT_proj  = WT_out + 65536;                                // 192 KB
    short* proj     = WT_proj + 4 * 96 * 256;                        // 25.2 MB

    // 0) weight prep: fp16, transposed, pre-swizzled
    prep_w<<<896, 256, 0, stream>>>(W_val, W_out, W_off, W_attn, WT_val, WT_out, WT_proj);

    // 1) value projection (fp32 in -> fp16 paired value2), BN=256
    gemm_mfma<0, 256, 4, 4, 4, 512><<<dim3(256, 1), 512, 0, stream>>>(
        input_fl, WT_val, b_val, nullptr, value2);

    // 2) offset/attn projection (16 GEMMs, fp32 in -> fp16 proj)
    gemm_mfma<2, 96, 1, 2, 6><<<dim3(64, 16), 256, 0, stream>>>(
        seq_query, WT_proj, b_off, b_attn, proj);

    // 3) softmax + bilinear sampling, per-(n,level) XCD pinning, 128B gathers
    sampler<<<(NB * LEN) / SQB * 4, 256, 0, stream>>>(
        proj, ref_pts, value2, out_part);

    // 4) output projection (sum of 4 partials, fp16 in -> fp32 d_out), BN=256
    gemm_mfma<4, 256, 4, 4, 4, 512><<<dim3(256, 1), 512, 0, stream>>>(
        out_part, WT_out, b_out, nullptr, out);
}